// Round 1
// 158.142 us; speedup vs baseline: 1.1113x; 1.1113x over previous
//
#include <hip/hip_runtime.h>

#define NNODES 100000
#define NEDGES 1600000
#define DIM 64
#define NB 782          // buckets of 128 nodes (dst >> 7); 782*128 = 100096
#define NPB 256         // partition blocks
#define CHUNK 6250      // edges per partition block (NPB * CHUNK == NEDGES)
#define CAP 3968        // padded slots per bucket (mean 2048, sigma 45)
#define HP 72           // hbuf pitch in SHORTS (144B rows: 16B-aligned, bank-spread)
#define NTILES 6250     // 100000 / 16 row-tiles
#define NSLICE 32       // BN partial-sum slices (contention 782 -> ~24 per address)

typedef __attribute__((ext_vector_type(4))) float f32x4;
typedef __attribute__((ext_vector_type(8))) short s16x8;   // 8 bf16 in 4 VGPRs

__device__ __forceinline__ unsigned short bf16_rne(float f) {
  unsigned u = __float_as_uint(f);
  u += 0x7FFF + ((u >> 16) & 1);
  return (unsigned short)(u >> 16);
}
__device__ __forceinline__ float bf16_to_f32(unsigned short h) {
  return __uint_as_float(((unsigned)h) << 16);
}

// ---------------- P0+P1 merged: x->bf16 convert + W pack + edge partition ---
// gcursor is now a pure COUNT per bucket (memset to 0 before launch); the
// bucket base t*CAP is added at address-computation time.
__global__ __launch_bounds__(1024) void prep_part_kernel(
    const float* __restrict__ x, unsigned short* __restrict__ xb,
    const int* __restrict__ ei, int* __restrict__ gcursor,
    int* __restrict__ bpart,
    const float* __restrict__ W1, const float* __restrict__ W2,
    unsigned short* __restrict__ Wp1, unsigned short* __restrict__ Wp2) {
  __shared__ int sd[1024];                  // histogram
  __shared__ int delta[1024];               // global_base - local_start
  __shared__ int lcur[1024];                // local scatter cursor
  __shared__ int wsum[16];                  // per-wave scan sums
  __shared__ int stage[CHUNK];              // bucket-sorted packed edges
  __shared__ unsigned short sbuck[CHUNK];   // bucket id per staged slot
  int t = threadIdx.x;
  sd[t] = 0;
  // --- x -> bf16, grid-strided; overlaps with all edge work below ---
  for (int i = blockIdx.x * 1024 + t; i < NNODES * DIM / 4; i += NPB * 1024) {
    float4 v = ((const float4*)x)[i];
    ushort4 o;
    o.x = bf16_rne(v.x); o.y = bf16_rne(v.y);
    o.z = bf16_rne(v.z); o.w = bf16_rne(v.w);
    ((ushort4*)xb)[i] = o;
  }
  // --- W pack (block 0 only). B-frag for mfma_f32_16x16x32_bf16:
  // lane L holds B[k=8*(L>>4)+j][n=L&15].
  if (blockIdx.x == 0 && t < 128) {
    int lane = t & 63;
    const float* W = (t >= 64) ? W2 : W1;
    unsigned short* Wp = (t >= 64) ? Wp2 : Wp1;
    int q = lane >> 4, n16 = lane & 15;
#pragma unroll
    for (int f = 0; f < 8; ++f) {
      int kk = f >> 2, nt = f & 3;
#pragma unroll
      for (int j = 0; j < 8; ++j) {
        int k = kk * 32 + q * 8 + j;
        int n = nt * 16 + n16;
        Wp[f * 512 + lane * 8 + j] = bf16_rne(W[k * DIM + n]);
      }
    }
  }
  __syncthreads();
  int base = blockIdx.x * CHUNK;
  // pass 1: histogram
  for (int i = t; i < CHUNK; i += 1024)
    atomicAdd(&sd[ei[NEDGES + base + i] >> 7], 1);
  __syncthreads();
  // wave-level inclusive scan (2 barriers instead of 20)
  int v = sd[t];
  int lane = t & 63;
  int incl = v;
#pragma unroll
  for (int off = 1; off < 64; off <<= 1) {
    int n = __shfl_up(incl, off);
    if (lane >= off) incl += n;
  }
  if (lane == 63) wsum[t >> 6] = incl;
  __syncthreads();
  if (t < 16) {
    int w = wsum[t];
#pragma unroll
    for (int off = 1; off < 16; off <<= 1) {
      int n = __shfl_up(w, off);
      if (t >= off) w += n;
    }
    wsum[t] = w;
  }
  __syncthreads();
  int wid = t >> 6;
  if (wid) incl += wsum[wid - 1];
  int excl = incl - v;                      // local run start
  delta[t] = (v ? (t * CAP + atomicAdd(&gcursor[t], v)) : 0) - excl;
  lcur[t] = excl;
  __syncthreads();
  // pass 2: scatter into LDS, bucket-sorted
  for (int i = t; i < CHUNK; i += 1024) {
    int s = ei[base + i];
    int d = ei[NEDGES + base + i];
    int b = d >> 7;
    int p = atomicAdd(&lcur[b], 1);
    stage[p] = ((d & 127) << 17) | s;       // src < 2^17, dlow bits 17..23
    sbuck[p] = (unsigned short)b;
  }
  __syncthreads();
  // flush: consecutive i -> consecutive global addresses within each run
  for (int i = t; i < CHUNK; i += 1024)
    bpart[delta[sbuck[i]] + i] = stage[i];
}

// ---------------- P2 MEGA: sort + paired-16B gather + GEMM1 + BN partials ---
__global__ __launch_bounds__(512) void mega_kernel(
    const int* __restrict__ bpart, const int* __restrict__ gcursor,
    const unsigned short* __restrict__ xb, float* __restrict__ h1,
    const unsigned short* __restrict__ Wp, const float* __restrict__ b1,
    const float* __restrict__ epsp,
    float* __restrict__ sums32, float* __restrict__ sumsq32) {
  __shared__ int sd[128];        // degree hist -> inclusive scan
  __shared__ int cur[128];       // scatter cursors
  __shared__ int swv[2];
  __shared__ int stage[CAP];     // sorted src list for this bucket
  __shared__ __align__(16) unsigned short hbuf[128 * HP];  // agg rows, bf16
  __shared__ float lsum[DIM];
  __shared__ float lsq[DIM];
  int b = blockIdx.x;
  int t = threadIdx.x;
  if (t < 128) sd[t] = 0;
  if (t < DIM) { lsum[t] = 0.0f; lsq[t] = 0.0f; }
  __syncthreads();
  int pbase = b * CAP;
  int cnt = gcursor[b];                     // count (cursor starts at 0)
  // --- phase A: counting sort into LDS stage ---
  for (int i = t; i < cnt; i += 512)
    atomicAdd(&sd[bpart[pbase + i] >> 17], 1);
  __syncthreads();
  // wave-level scan of 128 degrees (2 barriers instead of 14)
  int deg = 0, incl = 0;
  if (t < 128) {
    deg = sd[t];
    incl = deg;
#pragma unroll
    for (int off = 1; off < 64; off <<= 1) {
      int n = __shfl_up(incl, off);
      if ((t & 63) >= off) incl += n;
    }
    if ((t & 63) == 63) swv[t >> 6] = incl;
  }
  __syncthreads();
  if (t < 128) {
    if (t >= 64) incl += swv[0];
    sd[t] = incl;                           // inclusive scan
    cur[t] = incl - deg;                    // exclusive start
  }
  __syncthreads();
  for (int i = t; i < cnt; i += 512) {
    int v = bpart[pbase + i];
    int p = atomicAdd(&cur[v >> 17], 1);
    stage[p] = v & 0x1FFFF;
  }
  __syncthreads();
  // --- phase B: gather; 16-lane groups, 2 rows per 16B load instruction ---
  {
    int part = t & 7;                       // 16B chunk within row
    int half = (t >> 3) & 1;                // which edge of the pair
    int ng = t >> 4;                        // group 0..31
#pragma unroll 1
    for (int pass = 0; pass < 4; ++pass) {
      int nl = ng + pass * 32;              // local node 0..127
      int e0 = (nl == 0) ? 0 : sd[nl - 1];
      int e1 = sd[nl];
      f32x4 aA0 = {0.f,0.f,0.f,0.f}, aA1 = aA0, aB0 = aA0, aB1 = aA0;
      int e = e0;
      for (; e + 8 <= e1; e += 8) {         // 8 edges, 4 dwordx4 loads in flight
        int s0 = stage[e + 0 + half];
        int s1 = stage[e + 2 + half];
        int s2 = stage[e + 4 + half];
        int s3 = stage[e + 6 + half];
        s16x8 u0 = *(const s16x8*)(xb + (size_t)s0 * DIM + part * 8);
        s16x8 u1 = *(const s16x8*)(xb + (size_t)s1 * DIM + part * 8);
        s16x8 u2 = *(const s16x8*)(xb + (size_t)s2 * DIM + part * 8);
        s16x8 u3 = *(const s16x8*)(xb + (size_t)s3 * DIM + part * 8);
#pragma unroll
        for (int j = 0; j < 4; ++j) {
          aA0[j] += bf16_to_f32((unsigned short)u0[j]) +
                    bf16_to_f32((unsigned short)u2[j]);
          aA1[j] += bf16_to_f32((unsigned short)u0[j + 4]) +
                    bf16_to_f32((unsigned short)u2[j + 4]);
          aB0[j] += bf16_to_f32((unsigned short)u1[j]) +
                    bf16_to_f32((unsigned short)u3[j]);
          aB1[j] += bf16_to_f32((unsigned short)u1[j + 4]) +
                    bf16_to_f32((unsigned short)u3[j + 4]);
        }
      }
      for (; e + 2 <= e1; e += 2) {         // pair remainder
        int s = stage[e + half];
        s16x8 u = *(const s16x8*)(xb + (size_t)s * DIM + part * 8);
#pragma unroll
        for (int j = 0; j < 4; ++j) {
          aA0[j] += bf16_to_f32((unsigned short)u[j]);
          aA1[j] += bf16_to_f32((unsigned short)u[j + 4]);
        }
      }
      if (e < e1 && half == 0) {            // odd single edge
        int s = stage[e];
        s16x8 u = *(const s16x8*)(xb + (size_t)s * DIM + part * 8);
#pragma unroll
        for (int j = 0; j < 4; ++j) {
          aA0[j] += bf16_to_f32((unsigned short)u[j]);
          aA1[j] += bf16_to_f32((unsigned short)u[j + 4]);
        }
      }
      // combine slots, then combine halves across lane+8, write bf16 row
      float r[8];
#pragma unroll
      for (int j = 0; j < 4; ++j) {
        r[j] = aA0[j] + aB0[j];
        r[j + 4] = aA1[j] + aB1[j];
      }
      s16x8 o;
#pragma unroll
      for (int j = 0; j < 8; ++j)
        o[j] = (short)bf16_rne(r[j] + __shfl_down(r[j], 8));
      if (half == 0)
        *(s16x8*)&hbuf[nl * HP + part * 8] = o;
    }
  }
  __syncthreads();
  // --- phase C: MFMA GEMM1 per wave + h1 store + BN stat partials ---
  {
    int wave = t >> 6;
    int lane = t & 63;
    int tile = b * 8 + wave;
    if (tile < NTILES) {
      int q = lane >> 4;
      int r16 = lane & 15;
      float onep = 1.0f + epsp[0];
      s16x8 bf[8];
#pragma unroll
      for (int f = 0; f < 8; ++f)
        bf[f] = ((const s16x8*)Wp)[f * 64 + lane];
      int lrow = wave * 16 + r16;           // local row in hbuf
      int grow = b * 128 + lrow;            // global row
      const s16x8* xrow = (const s16x8*)(xb + (size_t)grow * DIM);
      f32x4 acc[4] = {{0.f,0.f,0.f,0.f},{0.f,0.f,0.f,0.f},
                      {0.f,0.f,0.f,0.f},{0.f,0.f,0.f,0.f}};
#pragma unroll
      for (int kk = 0; kk < 2; ++kk) {
        s16x8 xv = xrow[kk * 4 + q];
        s16x8 hv = *(const s16x8*)&hbuf[lrow * HP + kk * 32 + q * 8];
        s16x8 a;
#pragma unroll
        for (int j = 0; j < 8; ++j)
          a[j] = (short)bf16_rne(fmaf(onep,
                     bf16_to_f32((unsigned short)xv[j]),
                     bf16_to_f32((unsigned short)hv[j])));
#pragma unroll
        for (int nt = 0; nt < 4; ++nt)
          acc[nt] = __builtin_amdgcn_mfma_f32_16x16x32_bf16(
              a, bf[kk * 4 + nt], acc[nt], 0, 0, 0);
      }
      int orow = tile * 16 + q * 4;
#pragma unroll
      for (int nt = 0; nt < 4; ++nt) {
        int col = nt * 16 + r16;
        float bb = b1[col];
        float sl = 0.0f, ql = 0.0f;
#pragma unroll
        for (int r = 0; r < 4; ++r) {
          float v = acc[nt][r] + bb;
          h1[(size_t)(orow + r) * DIM + col] = v;
          sl += v;
          ql = fmaf(v, v, ql);
        }
        sl += __shfl_down(sl, 32); ql += __shfl_down(ql, 32);
        sl += __shfl_down(sl, 16); ql += __shfl_down(ql, 16);
        if (q == 0) {
          atomicAdd(&lsum[col], sl);
          atomicAdd(&lsq[col], ql);
        }
      }
    }
  }
  __syncthreads();
  if (t < DIM) {
    int sl = (b & (NSLICE - 1)) * DIM;      // 32-way sliced: contention /32
    atomicAdd(&sums32[sl + t], lsum[t]);
    atomicAdd(&sumsq32[sl + t], lsq[t]);
  }
}

// ---------------- fused2 (MFMA): out = relu(bn(h1)) @ W2 + b2 ---------------
__global__ __launch_bounds__(256) void fused2_kernel(
    const float* __restrict__ h1, float* __restrict__ out,
    const unsigned short* __restrict__ Wp, const float* __restrict__ b2,
    const float* __restrict__ gamma, const float* __restrict__ beta,
    const float* __restrict__ sums32, const float* __restrict__ sumsq32) {
  __shared__ float sc_s[DIM];
  __shared__ float sh_s[DIM];
  int t = threadIdx.x;
  if (t < DIM) {
    float s = 0.0f, q2 = 0.0f;
#pragma unroll
    for (int j = 0; j < NSLICE; ++j) {      // reduce the 32 slices (coalesced)
      s  += sums32[j * DIM + t];
      q2 += sumsq32[j * DIM + t];
    }
    float invN = 1.0f / (float)NNODES;
    float m = s * invN;
    float v = fmaf(-m, m, q2 * invN);
    float sc = gamma[t] * rsqrtf(v + 1e-5f);
    sc_s[t] = sc;
    sh_s[t] = fmaf(-m, sc, beta[t]);
  }
  __syncthreads();
  int wave = t >> 6;
  int lane = t & 63;
  int tile = blockIdx.x * 4 + wave;
  if (tile >= NTILES) return;
  int q = lane >> 4;
  int r16 = lane & 15;
  s16x8 bf[8];
#pragma unroll
  for (int f = 0; f < 8; ++f)
    bf[f] = ((const s16x8*)Wp)[f * 64 + lane];
  int arow = tile * 16 + r16;
  const float* hr = h1 + (size_t)arow * DIM + q * 8;
  f32x4 acc[4] = {{0.f,0.f,0.f,0.f},{0.f,0.f,0.f,0.f},
                  {0.f,0.f,0.f,0.f},{0.f,0.f,0.f,0.f}};
#pragma unroll
  for (int kk = 0; kk < 2; ++kk) {
    int kbase = kk * 32 + q * 8;
    float4 hv0 = *(const float4*)(hr + kk * 32);
    float4 hv1 = *(const float4*)(hr + kk * 32 + 4);
    float4 sc0 = *(const float4*)(sc_s + kbase);
    float4 sc1 = *(const float4*)(sc_s + kbase + 4);
    float4 sh0 = *(const float4*)(sh_s + kbase);
    float4 sh1 = *(const float4*)(sh_s + kbase + 4);
    s16x8 a;
    a[0] = (short)bf16_rne(fmaxf(fmaf(hv0.x, sc0.x, sh0.x), 0.f));
    a[1] = (short)bf16_rne(fmaxf(fmaf(hv0.y, sc0.y, sh0.y), 0.f));
    a[2] = (short)bf16_rne(fmaxf(fmaf(hv0.z, sc0.z, sh0.z), 0.f));
    a[3] = (short)bf16_rne(fmaxf(fmaf(hv0.w, sc0.w, sh0.w), 0.f));
    a[4] = (short)bf16_rne(fmaxf(fmaf(hv1.x, sc1.x, sh1.x), 0.f));
    a[5] = (short)bf16_rne(fmaxf(fmaf(hv1.y, sc1.y, sh1.y), 0.f));
    a[6] = (short)bf16_rne(fmaxf(fmaf(hv1.z, sc1.z, sh1.z), 0.f));
    a[7] = (short)bf16_rne(fmaxf(fmaf(hv1.w, sc1.w, sh1.w), 0.f));
#pragma unroll
    for (int nt = 0; nt < 4; ++nt)
      acc[nt] = __builtin_amdgcn_mfma_f32_16x16x32_bf16(
          a, bf[kk * 4 + nt], acc[nt], 0, 0, 0);
  }
  int orow = tile * 16 + q * 4;
#pragma unroll
  for (int nt = 0; nt < 4; ++nt) {
    int col = nt * 16 + r16;
    float bb = b2[col];
#pragma unroll
    for (int r = 0; r < 4; ++r)
      out[(size_t)(orow + r) * DIM + col] = acc[nt][r] + bb;
  }
}

extern "C" void kernel_launch(void* const* d_in, const int* in_sizes, int n_in,
                              void* d_out, int out_size, void* d_ws, size_t ws_size,
                              hipStream_t stream) {
  (void)in_sizes; (void)n_in; (void)out_size; (void)ws_size;
  const float* x     = (const float*)d_in[0];
  const int*   ei    = (const int*)d_in[1];
  const float* eps   = (const float*)d_in[2];
  const float* W1    = (const float*)d_in[3];
  const float* b1    = (const float*)d_in[4];
  const float* gamma = (const float*)d_in[5];
  const float* beta  = (const float*)d_in[6];
  const float* W2    = (const float*)d_in[7];
  const float* b2    = (const float*)d_in[8];
  float* outp = (float*)d_out;

  const int N = NNODES;

  // workspace (~25.64 MB)
  float* h1       = (float*)d_ws;                      // N*64 f32
  float* sums32   = h1 + (size_t)N * DIM;              // 32*64 f32 (memset 0)
  float* sumsq32  = sums32 + NSLICE * DIM;             // 32*64 f32 (memset 0)
  int*   gcursor  = (int*)(sumsq32 + NSLICE * DIM);    // 1024 int (memset 0)
  unsigned short* Wp1 = (unsigned short*)(gcursor + 1024);  // 4096 bf16 (16B-al)
  unsigned short* Wp2 = Wp1 + 4096;                         // 4096 bf16
  // d_out scratch (dead before fused2 overwrites it):
  //   bpart: NB*CAP ints = 12.41 MB ; xb: N*DIM bf16 = 12.80 MB (25.21<=25.6)
  int*            bpart = (int*)d_out;
  unsigned short* xb    = (unsigned short*)d_out + (size_t)NB * CAP * 2;

  hipMemsetAsync(sums32, 0,
                 (size_t)(2 * NSLICE * DIM) * sizeof(float) + 1024 * sizeof(int),
                 stream);
  prep_part_kernel<<<NPB, 1024, 0, stream>>>(x, xb, ei, gcursor, bpart,
                                             W1, W2, Wp1, Wp2);
  mega_kernel     <<<NB, 512, 0, stream>>>(bpart, gcursor, xb, h1,
                                           Wp1, b1, eps, sums32, sumsq32);
  fused2_kernel   <<<(NTILES + 3) / 4, 256, 0, stream>>>(h1, outp, Wp2, b2,
                                                         gamma, beta,
                                                         sums32, sumsq32);
}